// Round 3
// baseline (600.785 us; speedup 1.0000x reference)
//
#include <hip/hip_runtime.h>
#include <math.h>

#define NROW 16384   // B*N rows
#define NCOL 4096
#define CDIM 256
#define DKDIM 64
#define SCALE 0.125f // DK^-0.5

typedef float v4f __attribute__((ext_vector_type(4)));  // for nontemporal stores

// ---------------- Kernel 1: fused Q/K projection ----------------
// Output layout (both Q and K): T4[(b*16 + dg)*4096 + n] = proj[n][4*dg .. 4*dg+3]
// (b = batch, dg = d-group of 4, n = row within batch). This makes both the
// per-row register loads (lane-consecutive) and the per-col scalar loads
// (col-consecutive) in kernel 2 contiguous.
// Block: 512 threads = 8 waves. wave w: proj = w>>2 (0=Q,1=K), chunk = w&3
// (16 d's). Each block: 64 x-rows; lane = row-within-block.
// Inner loop: 1 ds_read_b128 (x) + scalar W loads + 64 scalar FMAs.
__global__ __launch_bounds__(512, 2) void qk_proj(
    const float* __restrict__ x, const float* __restrict__ Wq,
    const float* __restrict__ Wk, float* __restrict__ Qt,
    float* __restrict__ Kt) {
  __shared__ float4 xs4[64][65];  // row stride 65 f4-units -> bank-group spread
  const int t = threadIdx.x;
  const int rb = blockIdx.x;      // 256 blocks of 64 rows
  {
    const float4* xg = (const float4*)(x + (size_t)rb * 64 * CDIM);
    #pragma unroll
    for (int i = 0; i < 8; ++i) {
      int idx = i * 512 + t;      // 0..4095
      xs4[idx >> 6][idx & 63] = xg[idx];
    }
  }
  __syncthreads();

  const int lane = t & 63;
  const int wu = __builtin_amdgcn_readfirstlane(t >> 6);  // wave id, uniform
  const int proj = wu >> 2;
  const int chunk = wu & 3;       // d-chunk: d = chunk*16 .. +15
  const float* __restrict__ Wp = proj ? Wk : Wq;

  float acc[16];
  #pragma unroll
  for (int j = 0; j < 16; ++j) acc[j] = 0.f;

  #pragma unroll 4
  for (int cs = 0; cs < 64; ++cs) {        // 4 c's per step
    float4 xv = xs4[lane][cs];
    const float xc[4] = {xv.x, xv.y, xv.z, xv.w};
    #pragma unroll
    for (int i = 0; i < 4; ++i) {
      // uniform address -> scalar loads of W[(4cs+i)][chunk*16 .. +15]
      const float4* __restrict__ w4 =
          (const float4*)(Wp + (size_t)(cs * 4 + i) * DKDIM + chunk * 16);
      float4 wa = w4[0], wb = w4[1], wc = w4[2], wd = w4[3];
      float xi = xc[i];
      acc[0]  = fmaf(xi, wa.x, acc[0]);  acc[1]  = fmaf(xi, wa.y, acc[1]);
      acc[2]  = fmaf(xi, wa.z, acc[2]);  acc[3]  = fmaf(xi, wa.w, acc[3]);
      acc[4]  = fmaf(xi, wb.x, acc[4]);  acc[5]  = fmaf(xi, wb.y, acc[5]);
      acc[6]  = fmaf(xi, wb.z, acc[6]);  acc[7]  = fmaf(xi, wb.w, acc[7]);
      acc[8]  = fmaf(xi, wc.x, acc[8]);  acc[9]  = fmaf(xi, wc.y, acc[9]);
      acc[10] = fmaf(xi, wc.z, acc[10]); acc[11] = fmaf(xi, wc.w, acc[11]);
      acc[12] = fmaf(xi, wd.x, acc[12]); acc[13] = fmaf(xi, wd.y, acc[13]);
      acc[14] = fmaf(xi, wd.z, acc[14]); acc[15] = fmaf(xi, wd.w, acc[15]);
    }
  }

  const int gr = rb * 64 + lane;  // global row
  const int b = gr >> 12;
  const int n = gr & 4095;
  float4* __restrict__ Out4 = (float4*)(proj ? Kt : Qt);
  #pragma unroll
  for (int i = 0; i < 4; ++i) {
    int dg = chunk * 4 + i;
    float4 o = {acc[4 * i], acc[4 * i + 1], acc[4 * i + 2], acc[4 * i + 3]};
    Out4[(size_t)(b * 16 + dg) * 4096 + n] = o;  // lane-consecutive: coalesced
  }
}

// ---------------- Kernel 2: fused S = Q K^T + per-row top-8 ----------------
// Grid (256 rowblocks, 4 col-chunks of 1024). Block 256 thr = 4 waves.
// lane = row (Q row in 64 VGPRs); wave w owns 256-col stripe; K frags are
// wave-uniform -> scalar loads. Inner loop: pure v_fmac (no LDS, no vmem).
// Also zero-fills its 64x1024 output region (overlaps the HBM write floor).
__global__ __launch_bounds__(256, 4) void s_topk(
    const float* __restrict__ Qt, const float* __restrict__ Kt,
    float* __restrict__ out, float* __restrict__ wsv, int* __restrict__ wsi) {
  __shared__ float cv[64][33];
  __shared__ int   ci[64][33];
  const int t = threadIdx.x;
  const int rb = blockIdx.x;       // 0..255
  const int chunk = blockIdx.y;    // 0..3
  const int lane = t & 63;
  const int wu = __builtin_amdgcn_readfirstlane(t >> 6);  // wave id
  const int b = rb >> 6;
  const int nb = (rb & 63) * 64;   // row base within batch

  // 1) zero-fill my 64 x 1024 output region (fire-and-forget, nontemporal)
  {
    v4f z = {0.f, 0.f, 0.f, 0.f};
    v4f* o4 = (v4f*)out + (size_t)rb * 64 * 1024 + chunk * 256;
    #pragma unroll 8
    for (int i = 0; i < 64; ++i) {
      int g = i * 256 + t;         // 0..16383: 64 rows x 256 f4
      __builtin_nontemporal_store(z, &o4[(size_t)(g >> 8) * 1024 + (g & 255)]);
    }
  }

  // 2) my Q row into registers: 64 floats (16 float4), coalesced loads
  const float4* __restrict__ Qt4 = (const float4*)Qt;
  float4 qv[16];
  #pragma unroll
  for (int g = 0; g < 16; ++g)
    qv[g] = Qt4[(size_t)(b * 16 + g) * 4096 + nb + lane];

  // 3) per-lane top-8 state (cached min + its slot)
  float tv[8]; int ti[8]; float tmin = -INFINITY; int tmpos = 0;
  #pragma unroll
  for (int q = 0; q < 8; ++q) { tv[q] = -INFINITY; ti[q] = 0; }

  const float4* __restrict__ Kt4 = (const float4*)Kt;
  const int stripe = chunk * 1024 + wu * 256;  // my wave's col stripe base

  #pragma unroll 1
  for (int cg = 0; cg < 16; ++cg) {  // 16 col-groups of 16 cols
    const int cb = stripe + cg * 16;
    float acc[16];
    #pragma unroll
    for (int j = 0; j < 16; ++j) acc[j] = 0.f;
    #pragma unroll
    for (int g = 0; g < 16; ++g) {
      // uniform address -> scalar loads (K frag shared by all 64 lanes)
      const float4* __restrict__ kg = Kt4 + (size_t)(b * 16 + g) * 4096 + cb;
      const float4 qf = qv[g];
      #pragma unroll
      for (int j = 0; j < 16; ++j) {
        float4 kf = kg[j];
        acc[j] = fmaf(qf.x, kf.x, acc[j]);
        acc[j] = fmaf(qf.y, kf.y, acc[j]);
        acc[j] = fmaf(qf.z, kf.z, acc[j]);
        acc[j] = fmaf(qf.w, kf.w, acc[j]);
      }
    }
    // top-8 update (skip whole group if its max can't beat current min)
    float tmax = acc[0];
    #pragma unroll
    for (int j = 1; j < 16; ++j) tmax = fmaxf(tmax, acc[j]);
    if (tmax > tmin) {
      #pragma unroll
      for (int j = 0; j < 16; ++j) {
        float v = acc[j];
        if (v > tmin) {
          int col = cb + j;
          #pragma unroll
          for (int q = 0; q < 8; ++q)
            if (q == tmpos) { tv[q] = v; ti[q] = col; }
          tmin = tv[0]; tmpos = 0;
          #pragma unroll
          for (int q = 1; q < 8; ++q)
            if (tv[q] < tmin) { tmin = tv[q]; tmpos = q; }
        }
      }
    }
  }

  // 4) block merge: 4 waves x 8 candidates -> chunk-local top-8 per row
  #pragma unroll
  for (int q = 0; q < 8; ++q) {
    cv[lane][wu * 8 + q] = tv[q];
    ci[lane][wu * 8 + q] = ti[q];
  }
  __syncthreads();
  if (t < 64) {
    float rv[8]; int rid[8];
    #pragma unroll
    for (int q = 0; q < 8; ++q) { rv[q] = cv[t][q]; rid[q] = ci[t][q]; }
    float m = rv[0]; int mp = 0;
    #pragma unroll
    for (int q = 1; q < 8; ++q) if (rv[q] < m) { m = rv[q]; mp = q; }
    #pragma unroll
    for (int c = 8; c < 32; ++c) {
      float v = cv[t][c];
      if (v > m) {
        int col = ci[t][c];
        #pragma unroll
        for (int q = 0; q < 8; ++q) if (q == mp) { rv[q] = v; rid[q] = col; }
        m = rv[0]; mp = 0;
        #pragma unroll
        for (int q = 1; q < 8; ++q) if (rv[q] < m) { m = rv[q]; mp = q; }
      }
    }
    size_t gr = (size_t)rb * 64 + t;
    #pragma unroll
    for (int q = 0; q < 8; ++q) {
      wsv[gr * 32 + chunk * 8 + q] = rv[q];
      wsi[gr * 32 + chunk * 8 + q] = rid[q];
    }
  }
}

// ---------------- Kernel 3: merge 4 chunks, softmax, scatter ----------------
__global__ __launch_bounds__(256) void merge_scatter(
    const float* __restrict__ wsv, const int* __restrict__ wsi,
    float* __restrict__ out) {
  int row = blockIdx.x * 256 + threadIdx.x;  // 0..16383
  float v[32]; int id[32];
  const float4* v4 = (const float4*)(wsv + (size_t)row * 32);
  const int4*   i4 = (const int4*)(wsi + (size_t)row * 32);
  #pragma unroll
  for (int i = 0; i < 8; ++i) {
    float4 a = v4[i]; v[4*i] = a.x; v[4*i+1] = a.y; v[4*i+2] = a.z; v[4*i+3] = a.w;
    int4   c = i4[i]; id[4*i] = c.x; id[4*i+1] = c.y; id[4*i+2] = c.z; id[4*i+3] = c.w;
  }
  float rv[8]; int rid[8];
  #pragma unroll
  for (int q = 0; q < 8; ++q) { rv[q] = v[q]; rid[q] = id[q]; }
  float m = rv[0]; int mp = 0;
  #pragma unroll
  for (int q = 1; q < 8; ++q) if (rv[q] < m) { m = rv[q]; mp = q; }
  #pragma unroll
  for (int c = 8; c < 32; ++c) {
    if (v[c] > m) {
      #pragma unroll
      for (int q = 0; q < 8; ++q) if (q == mp) { rv[q] = v[c]; rid[q] = id[c]; }
      m = rv[0]; mp = 0;
      #pragma unroll
      for (int q = 1; q < 8; ++q) if (rv[q] < m) { m = rv[q]; mp = q; }
    }
  }
  float vmax = rv[0];
  #pragma unroll
  for (int q = 1; q < 8; ++q) vmax = fmaxf(vmax, rv[q]);
  float e[8], s = 0.f;
  #pragma unroll
  for (int q = 0; q < 8; ++q) { e[q] = __expf((rv[q] - vmax) * SCALE); s += e[q]; }
  float inv = 1.f / s;
  float* orow = out + (size_t)row * NCOL;
  #pragma unroll
  for (int q = 0; q < 8; ++q) orow[rid[q]] = e[q] * inv;
}

extern "C" void kernel_launch(void* const* d_in, const int* in_sizes, int n_in,
                              void* d_out, int out_size, void* d_ws, size_t ws_size,
                              hipStream_t stream) {
  const float* x  = (const float*)d_in[0];
  const float* Wq = (const float*)d_in[1];
  const float* Wk = (const float*)d_in[2];
  float* out = (float*)d_out;

  char* ws = (char*)d_ws;
  float* Qt  = (float*)ws;                                   // 4 MB
  float* Kt  = (float*)(ws + (size_t)NROW * DKDIM * 4);      // 4 MB
  float* wsv = (float*)(ws + 2 * (size_t)NROW * DKDIM * 4);  // 2 MB
  int*   wsi = (int*)  (ws + 2 * (size_t)NROW * DKDIM * 4 + (size_t)NROW * 32 * 4); // 2 MB

  qk_proj<<<dim3(NROW / 64), 512, 0, stream>>>(x, Wq, Wk, Qt, Kt);
  s_topk<<<dim3(NROW / 64, 4), 256, 0, stream>>>(Qt, Kt, out, wsv, wsi);
  merge_scatter<<<NROW / 256, 256, 0, stream>>>(wsv, wsi, out);
}